// Round 1
// baseline (4994.038 us; speedup 1.0000x reference)
//
#include <hip/hip_runtime.h>
#include <math.h>

#define DIMS 1024
#define NH 16
#define HD 64
#define BATCH 8
#define SEQ 1024
#define MROWS (BATCH * SEQ)   // 8192
#define FFDIM 2048
#define LNEPS 1e-5f

// ---------------------------------------------------------------------------
// Generic tiled f32 GEMM:  C[m,n] = (sum_k A[m,k]*W[n,k] + bias[n]) * alpha
// A: M x K row-major, W: N x K row-major (torch Linear layout), C: M x N.
// 64x64 tile, BK=16, 256 threads, 4x4 accumulators per thread.
// ---------------------------------------------------------------------------
#define BM 64
#define BN 64
#define BK 16

template <bool RELU>
__global__ __launch_bounds__(256) void gemm_nt(
    const float* __restrict__ A, const float* __restrict__ W,
    const float* __restrict__ bias, float* __restrict__ C,
    int M, int N, int K, float alpha)
{
    __shared__ float sA[BK][BM + 1];
    __shared__ float sB[BK][BN + 1];

    const int tid = threadIdx.x;
    const int bm = blockIdx.y * BM;
    const int bn = blockIdx.x * BN;

    const int tr = (tid / 16) * 4;   // 0..60, row offset in tile
    const int tc = (tid % 16) * 4;   // 0..60, col offset in tile

    const int lr = tid >> 2;         // 0..63, load row
    const int lk = (tid & 3) * 4;    // 0,4,8,12, load k offset

    float acc[4][4] = {};

    for (int k0 = 0; k0 < K; k0 += BK) {
        float4 a4 = *reinterpret_cast<const float4*>(&A[(size_t)(bm + lr) * K + k0 + lk]);
        float4 b4 = *reinterpret_cast<const float4*>(&W[(size_t)(bn + lr) * K + k0 + lk]);
        __syncthreads();             // previous iteration's reads done
        sA[lk + 0][lr] = a4.x; sA[lk + 1][lr] = a4.y;
        sA[lk + 2][lr] = a4.z; sA[lk + 3][lr] = a4.w;
        sB[lk + 0][lr] = b4.x; sB[lk + 1][lr] = b4.y;
        sB[lk + 2][lr] = b4.z; sB[lk + 3][lr] = b4.w;
        __syncthreads();
#pragma unroll
        for (int kk = 0; kk < BK; ++kk) {
            float a[4], b[4];
#pragma unroll
            for (int i = 0; i < 4; ++i) a[i] = sA[kk][tr + i];
#pragma unroll
            for (int j = 0; j < 4; ++j) b[j] = sB[kk][tc + j];
#pragma unroll
            for (int i = 0; i < 4; ++i)
#pragma unroll
                for (int j = 0; j < 4; ++j)
                    acc[i][j] = fmaf(a[i], b[j], acc[i][j]);
        }
    }

#pragma unroll
    for (int i = 0; i < 4; ++i) {
#pragma unroll
        for (int j = 0; j < 4; ++j) {
            float v = (acc[i][j] + bias[bn + tc + j]) * alpha;
            if (RELU) v = fmaxf(v, 0.0f);
            C[(size_t)(bm + tr + i) * N + bn + tc + j] = v;
        }
    }
}

// ---------------------------------------------------------------------------
// Fused attention: per block = one (b,h) and 16 query rows.
//   QK^T (K streamed in 256-row chunks) -> masked softmax in LDS ->
//   write normalized scores to global -> PV (V streamed) -> attn-out.
// q is pre-scaled by 1/sqrt(HD) in its projection GEMM.
// ---------------------------------------------------------------------------
#define AROWS 16
#define CHUNK 256

__global__ __launch_bounds__(256) void attn_fused(
    const float* __restrict__ q, const float* __restrict__ kx,
    const float* __restrict__ vx, float* __restrict__ score,
    float* __restrict__ ao)
{
    const int bh = blockIdx.y;       // 0..127
    const int b  = bh >> 4;
    const int h  = bh & 15;
    const int i0 = blockIdx.x * AROWS;
    const int tid = threadIdx.x;

    __shared__ float sQ[AROWS][HD];          //  4 KB
    __shared__ float sT[CHUNK][HD + 2];      // ~66 KB (K or V chunk)
    __shared__ float sS[AROWS][SEQ];         // 64 KB (scores for 16 rows)

    const size_t rowbase = (size_t)b * SEQ * DIMS + (size_t)h * HD;

    // ---- load Q tile (16 x 64) ----
    {
        int r = tid >> 4, c = (tid & 15) * 4;
        float4 t = *reinterpret_cast<const float4*>(
            &q[rowbase + (size_t)(i0 + r) * DIMS + c]);
        sQ[r][c + 0] = t.x; sQ[r][c + 1] = t.y;
        sQ[r][c + 2] = t.z; sQ[r][c + 3] = t.w;
    }

    // ---- QK^T over 4 chunks of 256 keys ----
    const int sub = tid >> 6;            // wave id: which 64-col subchunk
    const int t64 = tid & 63;
    const int tr4 = (t64 >> 4) * 4;      // rows 0,4,8,12
    const int tc4 = (t64 & 15) * 4;      // cols 0..60 within subchunk

    for (int c0 = 0; c0 < SEQ; c0 += CHUNK) {
        __syncthreads();
        {
            int rr = tid >> 4, cc = (tid & 15) * 4;
#pragma unroll
            for (int p = 0; p < CHUNK; p += 16) {
                float4 t = *reinterpret_cast<const float4*>(
                    &kx[rowbase + (size_t)(c0 + p + rr) * DIMS + cc]);
                sT[p + rr][cc + 0] = t.x; sT[p + rr][cc + 1] = t.y;
                sT[p + rr][cc + 2] = t.z; sT[p + rr][cc + 3] = t.w;
            }
        }
        __syncthreads();

        float acc[4][4] = {};
#pragma unroll 16
        for (int d = 0; d < HD; ++d) {
            float a[4], bb[4];
#pragma unroll
            for (int i = 0; i < 4; ++i) a[i] = sQ[tr4 + i][d];
#pragma unroll
            for (int j = 0; j < 4; ++j) bb[j] = sT[sub * 64 + tc4 + j][d];
#pragma unroll
            for (int i = 0; i < 4; ++i)
#pragma unroll
                for (int j = 0; j < 4; ++j)
                    acc[i][j] = fmaf(a[i], bb[j], acc[i][j]);
        }
#pragma unroll
        for (int i = 0; i < 4; ++i)
#pragma unroll
            for (int j = 0; j < 4; ++j)
                sS[tr4 + i][c0 + sub * 64 + tc4 + j] = acc[i][j];
    }
    __syncthreads();

    // ---- masked softmax (col SEQ-1 masked to -inf -> prob 0) ----
    {
        int r = tid >> 4, l = tid & 15;   // 16 contiguous lanes per row
        float m = -INFINITY;
        for (int j = l; j < SEQ - 1; j += 16) m = fmaxf(m, sS[r][j]);
#pragma unroll
        for (int off = 8; off; off >>= 1) m = fmaxf(m, __shfl_xor(m, off, 16));
        float s = 0.0f;
        for (int j = l; j < SEQ - 1; j += 16) {
            float e = expf(sS[r][j] - m);
            sS[r][j] = e;
            s += e;
        }
#pragma unroll
        for (int off = 8; off; off >>= 1) s += __shfl_xor(s, off, 16);
        float inv = 1.0f / s;
        for (int j = l; j < SEQ - 1; j += 16) sS[r][j] *= inv;
        if (l == 0) sS[r][SEQ - 1] = 0.0f;
    }
    __syncthreads();

    // ---- write normalized scores ----
    {
        size_t sbase = ((size_t)bh * SEQ + i0) * SEQ;
        int r = tid >> 4, c = (tid & 15) * 4;
#pragma unroll
        for (int p = 0; p < SEQ; p += 64) {
            float4 t = { sS[r][p + c], sS[r][p + c + 1],
                         sS[r][p + c + 2], sS[r][p + c + 3] };
            *reinterpret_cast<float4*>(&score[sbase + (size_t)r * SEQ + p + c]) = t;
        }
    }

    // ---- PV: out[16][64] = P @ V ----
    {
        int r = tid >> 4;            // 0..15
        int d4 = (tid & 15) * 4;     // 0..60
        float o[4] = {0.f, 0.f, 0.f, 0.f};
        for (int c0 = 0; c0 < SEQ; c0 += CHUNK) {
            __syncthreads();
            {
                int rr = tid >> 4, cc = (tid & 15) * 4;
#pragma unroll
                for (int p = 0; p < CHUNK; p += 16) {
                    float4 t = *reinterpret_cast<const float4*>(
                        &vx[rowbase + (size_t)(c0 + p + rr) * DIMS + cc]);
                    sT[p + rr][cc + 0] = t.x; sT[p + rr][cc + 1] = t.y;
                    sT[p + rr][cc + 2] = t.z; sT[p + rr][cc + 3] = t.w;
                }
            }
            __syncthreads();
#pragma unroll 8
            for (int j = 0; j < CHUNK; ++j) {
                float p = sS[r][c0 + j];
                o[0] = fmaf(p, sT[j][d4 + 0], o[0]);
                o[1] = fmaf(p, sT[j][d4 + 1], o[1]);
                o[2] = fmaf(p, sT[j][d4 + 2], o[2]);
                o[3] = fmaf(p, sT[j][d4 + 3], o[3]);
            }
        }
        float4 t = {o[0], o[1], o[2], o[3]};
        *reinterpret_cast<float4*>(&ao[rowbase + (size_t)(i0 + r) * DIMS + d4]) = t;
    }
}

// ---------------------------------------------------------------------------
// out = LayerNorm(A + B) * g + be   (one block per row of 1024)
// ---------------------------------------------------------------------------
__global__ __launch_bounds__(256) void add_ln(
    const float* __restrict__ A, const float* __restrict__ Bv,
    const float* __restrict__ g, const float* __restrict__ be,
    float* __restrict__ out)
{
    const int row = blockIdx.x;
    const int tid = threadIdx.x;
    const size_t base = (size_t)row * DIMS + tid * 4;

    float4 a = *reinterpret_cast<const float4*>(&A[base]);
    float4 b = *reinterpret_cast<const float4*>(&Bv[base]);
    float x0 = a.x + b.x, x1 = a.y + b.y, x2 = a.z + b.z, x3 = a.w + b.w;

    float s = x0 + x1 + x2 + x3;
#pragma unroll
    for (int off = 32; off; off >>= 1) s += __shfl_xor(s, off, 64);

    __shared__ float red1[4];
    __shared__ float red2[4];
    const int wave = tid >> 6, lane = tid & 63;
    if (lane == 0) red1[wave] = s;
    __syncthreads();
    const float mean = (red1[0] + red1[1] + red1[2] + red1[3]) * (1.0f / DIMS);

    x0 -= mean; x1 -= mean; x2 -= mean; x3 -= mean;
    float vs = x0 * x0 + x1 * x1 + x2 * x2 + x3 * x3;
#pragma unroll
    for (int off = 32; off; off >>= 1) vs += __shfl_xor(vs, off, 64);
    if (lane == 0) red2[wave] = vs;
    __syncthreads();
    const float var = (red2[0] + red2[1] + red2[2] + red2[3]) * (1.0f / DIMS);
    const float rs = rsqrtf(var + LNEPS);

    const int c = tid * 4;
    float4 gg = *reinterpret_cast<const float4*>(&g[c]);
    float4 bb = *reinterpret_cast<const float4*>(&be[c]);
    float4 o = { x0 * rs * gg.x + bb.x, x1 * rs * gg.y + bb.y,
                 x2 * rs * gg.z + bb.z, x3 * rs * gg.w + bb.w };
    *reinterpret_cast<float4*>(&out[base]) = o;
}

// ---------------------------------------------------------------------------
extern "C" void kernel_launch(void* const* d_in, const int* in_sizes, int n_in,
                              void* d_out, int out_size, void* d_ws, size_t ws_size,
                              hipStream_t stream)
{
    const float* x   = (const float*)d_in[0];
    const float* Wq  = (const float*)d_in[1];
    const float* bq  = (const float*)d_in[2];
    const float* Wk  = (const float*)d_in[3];
    const float* bk  = (const float*)d_in[4];
    const float* Wv  = (const float*)d_in[5];
    const float* bv  = (const float*)d_in[6];
    const float* Wf  = (const float*)d_in[7];
    const float* bf  = (const float*)d_in[8];
    const float* W1  = (const float*)d_in[9];
    const float* b1  = (const float*)d_in[10];
    const float* W2  = (const float*)d_in[11];
    const float* b2  = (const float*)d_in[12];
    const float* g1  = (const float*)d_in[13];
    const float* be1 = (const float*)d_in[14];
    const float* g2  = (const float*)d_in[15];
    const float* be2 = (const float*)d_in[16];

    float* out   = (float*)d_out;                       // MROWS*DIMS
    float* score = out + (size_t)MROWS * DIMS;          // B*H*S*S

    const size_t MD = (size_t)MROWS * DIMS;             // 8,388,608
    float* ws = (float*)d_ws;
    float* q  = ws;              // [0, MD)
    float* k  = ws + MD;         // [MD, 2MD)
    float* v  = ws + 2 * MD;     // [2MD, 3MD)
    float* ao = ws + 3 * MD;     // [3MD, 4MD)
    float* ap = ws;              // reuse q slot
    float* y  = ws + MD;         // reuse k slot
    float* h1 = ws + 2 * MD;     // reuse v+ao slots (2*MD floats)
    float* f2 = ws;              // reuse ap slot

    const dim3 blk(256);
    const dim3 gP(DIMS / BN, MROWS / BM);      // (16,128) N=1024
    const dim3 gF1(FFDIM / BN, MROWS / BM);    // (32,128) N=2048

    // QKV projections (q scaled by 1/sqrt(HD))
    gemm_nt<false><<<gP, blk, 0, stream>>>(x, Wq, bq, q, MROWS, DIMS, DIMS, 0.125f);
    gemm_nt<false><<<gP, blk, 0, stream>>>(x, Wk, bk, k, MROWS, DIMS, DIMS, 1.0f);
    gemm_nt<false><<<gP, blk, 0, stream>>>(x, Wv, bv, v, MROWS, DIMS, DIMS, 1.0f);

    // fused attention (scores + softmax + PV)
    attn_fused<<<dim3(SEQ / AROWS, BATCH * NH), blk, 0, stream>>>(q, k, v, score, ao);

    // output projection + first add+LN
    gemm_nt<false><<<gP, blk, 0, stream>>>(ao, Wf, bf, ap, MROWS, DIMS, DIMS, 1.0f);
    add_ln<<<dim3(MROWS), blk, 0, stream>>>(x, ap, g1, be1, y);

    // FFN
    gemm_nt<true ><<<gF1, blk, 0, stream>>>(y, W1, b1, h1, MROWS, FFDIM, DIMS, 1.0f);
    gemm_nt<false><<<gP,  blk, 0, stream>>>(h1, W2, b2, f2, MROWS, DIMS, FFDIM, 1.0f);
    add_ln<<<dim3(MROWS), blk, 0, stream>>>(y, f2, g2, be2, out);
}

// Round 3
// 1227.135 us; speedup vs baseline: 4.0697x; 4.0697x over previous
//
#include <hip/hip_runtime.h>
#include <math.h>

#define DIMS 1024
#define NH 16
#define HD 64
#define BATCH 8
#define SEQ 1024
#define MROWS (BATCH * SEQ)   // 8192
#define FFDIM 2048
#define LNEPS 1e-5f

typedef __bf16 bf16_t;
typedef __bf16 bf16x8 __attribute__((ext_vector_type(8)));
typedef __bf16 bf16x4 __attribute__((ext_vector_type(4)));
typedef float  f32x4  __attribute__((ext_vector_type(4)));

typedef __attribute__((address_space(3))) void       lds_void;
typedef const __attribute__((address_space(1))) void glb_void;

__device__ __forceinline__ void gld_lds16(const bf16_t* g, bf16_t* l) {
    __builtin_amdgcn_global_load_lds((glb_void*)g, (lds_void*)l, 16, 0, 0);
}

#define MFMA16(a, b, c) __builtin_amdgcn_mfma_f32_16x16x32_bf16(a, b, c, 0, 0, 0)

// ---------------------------------------------------------------------------
// f32 -> bf16 cast, 8 elems/thread
// ---------------------------------------------------------------------------
__global__ __launch_bounds__(256) void castk(const float* __restrict__ in,
                                             bf16_t* __restrict__ o, int n8)
{
    int i = blockIdx.x * 256 + threadIdx.x;
    if (i < n8) {
        float4 a = *reinterpret_cast<const float4*>(&in[(size_t)i * 8]);
        float4 b = *reinterpret_cast<const float4*>(&in[(size_t)i * 8 + 4]);
        bf16x8 v = {(__bf16)a.x, (__bf16)a.y, (__bf16)a.z, (__bf16)a.w,
                    (__bf16)b.x, (__bf16)b.y, (__bf16)b.z, (__bf16)b.w};
        *reinterpret_cast<bf16x8*>(&o[(size_t)i * 8]) = v;
    }
}

// ---------------------------------------------------------------------------
// bf16 MFMA GEMM-NT: C = (A @ B^T + bias) * alpha, A: MxK (lda), B: NxK (ldb)
// 128x128 tile, BK=32, 4 waves, each wave a 64x64 quadrant (4x4 MFMA frags).
// m97-style: global_load_lds staging, 2 barriers per K-step.
// ATTN: batched over blockIdx.z = bh (A/B offset b*S*D + h*HD, C offset z*S*S)
// ---------------------------------------------------------------------------
template <bool OUT_BF16, bool RELU, bool ATTN>
__global__ __launch_bounds__(256, 2) void gemm_bt(
    const bf16_t* __restrict__ A, const bf16_t* __restrict__ B,
    const float* __restrict__ bs, void* __restrict__ Cv,
    int M, int N, int K, int lda, int ldb, int ldc, float alpha)
{
    __shared__ bf16_t sA[128 * 32];
    __shared__ bf16_t sB[128 * 32];

    const int tid = threadIdx.x;
    const int wv = tid >> 6, ln = tid & 63;
    const int bm = blockIdx.y * 128, bn = blockIdx.x * 128;

    size_t cbase = 0;
    if (ATTN) {
        int z = blockIdx.z;
        size_t aoff = (size_t)(z >> 4) * (SEQ * DIMS) + (size_t)(z & 15) * HD;
        A += aoff; B += aoff;
        cbase = (size_t)z * SEQ * SEQ;
    }

    // staging: chunk (s*4+wv) covers LDS rows [chunk*16, chunk*16+16)
    const int rlo = wv * 16 + (ln >> 2);
    const int kc = (ln & 3) * 8;
    const bf16_t* A0 = A + (size_t)(bm + rlo) * lda + kc;
    const bf16_t* A1 = A + (size_t)(bm + rlo + 64) * lda + kc;
    const bf16_t* B0 = B + (size_t)(bn + rlo) * ldb + kc;
    const bf16_t* B1 = B + (size_t)(bn + rlo + 64) * ldb + kc;
    bf16_t* lA0 = &sA[(0 * 4 + wv) * 512];
    bf16_t* lA1 = &sA[(1 * 4 + wv) * 512];
    bf16_t* lB0 = &sB[(0 * 4 + wv) * 512];
    bf16_t* lB1 = &sB[(1 * 4 + wv) * 512];

    const int wr = (wv >> 1) * 64, wc = (wv & 1) * 64;
    const int fr = ln & 15, fq = ln >> 4;

    f32x4 acc[4][4] = {};

    for (int k0 = 0; k0 < K; k0 += 32) {
        __syncthreads();
        gld_lds16(A0 + k0, lA0);
        gld_lds16(A1 + k0, lA1);
        gld_lds16(B0 + k0, lB0);
        gld_lds16(B1 + k0, lB1);
        __syncthreads();   // compiler emits vmcnt(0) drain before barrier

        bf16x8 af[4], bfq[4];
#pragma unroll
        for (int i = 0; i < 4; ++i)
            af[i] = *reinterpret_cast<const bf16x8*>(&sA[(wr + i * 16 + fr) * 32 + fq * 8]);
#pragma unroll
        for (int j = 0; j < 4; ++j)
            bfq[j] = *reinterpret_cast<const bf16x8*>(&sB[(wc + j * 16 + fr) * 32 + fq * 8]);
#pragma unroll
        for (int i = 0; i < 4; ++i)
#pragma unroll
            for (int j = 0; j < 4; ++j)
                acc[i][j] = MFMA16(af[i], bfq[j], acc[i][j]);
    }

    // epilogue: C/D layout col = lane&15, row = (lane>>4)*4 + e  [m89/m91]
#pragma unroll
    for (int i = 0; i < 4; ++i) {
#pragma unroll
        for (int j = 0; j < 4; ++j) {
            int col = bn + wc + j * 16 + fr;
            float bias = bs ? bs[col] : 0.0f;
#pragma unroll
            for (int e = 0; e < 4; ++e) {
                int row = bm + wr + i * 16 + fq * 4 + e;
                float v = (acc[i][j][e] + bias) * alpha;
                if (RELU) v = fmaxf(v, 0.0f);
                if (OUT_BF16)
                    ((bf16_t*)Cv)[cbase + (size_t)row * ldc + col] = (__bf16)v;
                else
                    ((float*)Cv)[cbase + (size_t)row * ldc + col] = v;
            }
        }
    }
}

// ---------------------------------------------------------------------------
// V transpose: vt[bh][d][s] <- v[b][s][h*64+d]   (64x64 tiles via LDS)
// ---------------------------------------------------------------------------
__global__ __launch_bounds__(256) void vtrans(const bf16_t* __restrict__ v,
                                              bf16_t* __restrict__ vt)
{
    __shared__ bf16_t tile[64 * 72];
    const int bh = blockIdx.y, s0 = blockIdx.x * 64;
    const int b = bh >> 4, h = bh & 15;
    const int tid = threadIdx.x;
    const bf16_t* vb = v + (size_t)b * (SEQ * DIMS) + (size_t)s0 * DIMS + h * HD;

#pragma unroll
    for (int vv = 0; vv < 2; ++vv) {
        int j = tid + 256 * vv;            // 0..511
        int r = j >> 3, cb = (j & 7) * 8;
        *reinterpret_cast<bf16x8*>(&tile[r * 72 + cb]) =
            *reinterpret_cast<const bf16x8*>(&vb[(size_t)r * DIMS + cb]);
    }
    __syncthreads();
    bf16_t* vto = vt + (size_t)bh * (HD * SEQ) + s0;
#pragma unroll
    for (int vv = 0; vv < 2; ++vv) {
        int j = tid + 256 * vv;
        int d = j >> 3, kb = (j & 7) * 8;
        bf16x8 o;
#pragma unroll
        for (int e = 0; e < 8; ++e) o[e] = tile[(kb + e) * 72 + d];
        *reinterpret_cast<bf16x8*>(&vto[(size_t)d * SEQ + kb]) = o;
    }
}

// ---------------------------------------------------------------------------
// attn2: per (bh, 16 q-rows): read raw logits from score, softmax in regs
// (16 lanes/row), write normalized f32 probs back, bf16 P into LDS, then
// PV via MFMA against vt (LDS-staged, padded). Wave w handles dims [16w,16w+16).
// ---------------------------------------------------------------------------
__global__ __launch_bounds__(256, 2) void attn2(
    float* score, const bf16_t* __restrict__ vt, bf16_t* __restrict__ ao)
{
    __shared__ bf16_t sP[16 * 1032];
    __shared__ bf16_t sVT[64 * 72];

    const int bh = blockIdx.y, i0 = blockIdx.x * 16;
    const int b = bh >> 4, h = bh & 15;
    const int tid = threadIdx.x;
    const int row = tid >> 4, l16 = tid & 15;
    const size_t srow = ((size_t)bh * SEQ + i0 + row) * SEQ;

    float4 lv[16];
#pragma unroll
    for (int jj = 0; jj < 16; ++jj)
        lv[jj] = *reinterpret_cast<const float4*>(&score[srow + l16 * 4 + 64 * jj]);
    if (l16 == 15) lv[15].w = -INFINITY;   // mask last key

    float m = -INFINITY;
#pragma unroll
    for (int jj = 0; jj < 16; ++jj)
        m = fmaxf(m, fmaxf(fmaxf(lv[jj].x, lv[jj].y), fmaxf(lv[jj].z, lv[jj].w)));
#pragma unroll
    for (int off = 8; off; off >>= 1) m = fmaxf(m, __shfl_xor(m, off, 16));

    float s = 0.0f;
#pragma unroll
    for (int jj = 0; jj < 16; ++jj) {
        lv[jj].x = __expf(lv[jj].x - m); lv[jj].y = __expf(lv[jj].y - m);
        lv[jj].z = __expf(lv[jj].z - m); lv[jj].w = __expf(lv[jj].w - m);
        s += lv[jj].x + lv[jj].y + lv[jj].z + lv[jj].w;
    }
#pragma unroll
    for (int off = 8; off; off >>= 1) s += __shfl_xor(s, off, 16);
    const float inv = 1.0f / s;

#pragma unroll
    for (int jj = 0; jj < 16; ++jj) {
        lv[jj].x *= inv; lv[jj].y *= inv; lv[jj].z *= inv; lv[jj].w *= inv;
        *reinterpret_cast<float4*>(&score[srow + l16 * 4 + 64 * jj]) = lv[jj];
        bf16x4 pk = {(__bf16)lv[jj].x, (__bf16)lv[jj].y,
                     (__bf16)lv[jj].z, (__bf16)lv[jj].w};
        *reinterpret_cast<bf16x4*>(&sP[row * 1032 + l16 * 4 + 64 * jj]) = pk;
    }

    // ---- PV ----
    const int wv = tid >> 6, l = tid & 63, fr = l & 15, fq = l >> 4;
    f32x4 acc = {0.f, 0.f, 0.f, 0.f};
    const bf16_t* vtb = vt + (size_t)bh * (HD * SEQ);

    for (int c0 = 0; c0 < SEQ; c0 += 64) {
        __syncthreads();
#pragma unroll
        for (int vv = 0; vv < 2; ++vv) {
            int j = tid + 256 * vv;
            int d = j >> 3, kb = (j & 7) * 8;
            *reinterpret_cast<bf16x8*>(&sVT[d * 72 + kb]) =
                *reinterpret_cast<const bf16x8*>(&vtb[(size_t)d * SEQ + c0 + kb]);
        }
        __syncthreads();
#pragma unroll
        for (int ks = 0; ks < 2; ++ks) {
            bf16x8 a = *reinterpret_cast<const bf16x8*>(
                &sP[fr * 1032 + c0 + ks * 32 + fq * 8]);
            bf16x8 bb = *reinterpret_cast<const bf16x8*>(
                &sVT[(wv * 16 + fr) * 72 + ks * 32 + fq * 8]);
            acc = MFMA16(a, bb, acc);
        }
    }

#pragma unroll
    for (int e = 0; e < 4; ++e) {
        int qr = fq * 4 + e, dcol = wv * 16 + fr;
        ao[(size_t)b * (SEQ * DIMS) + (size_t)(i0 + qr) * DIMS + h * HD + dcol] =
            (__bf16)acc[e];
    }
}

// ---------------------------------------------------------------------------
// out = LayerNorm(A + B) * g + be ; optionally also bf16 copy
// ---------------------------------------------------------------------------
template <bool DUAL>
__global__ __launch_bounds__(256) void add_ln(
    const float* __restrict__ A, const float* __restrict__ Bv,
    const float* __restrict__ g, const float* __restrict__ be,
    float* __restrict__ outp, bf16_t* __restrict__ outb)
{
    const int row = blockIdx.x;
    const int tid = threadIdx.x;
    const size_t base = (size_t)row * DIMS + tid * 4;

    float4 a = *reinterpret_cast<const float4*>(&A[base]);
    float4 b = *reinterpret_cast<const float4*>(&Bv[base]);
    float x0 = a.x + b.x, x1 = a.y + b.y, x2 = a.z + b.z, x3 = a.w + b.w;

    float s = x0 + x1 + x2 + x3;
#pragma unroll
    for (int off = 32; off; off >>= 1) s += __shfl_xor(s, off, 64);

    __shared__ float red1[4];
    __shared__ float red2[4];
    const int wave = tid >> 6, lane = tid & 63;
    if (lane == 0) red1[wave] = s;
    __syncthreads();
    const float mean = (red1[0] + red1[1] + red1[2] + red1[3]) * (1.0f / DIMS);

    x0 -= mean; x1 -= mean; x2 -= mean; x3 -= mean;
    float vs = x0 * x0 + x1 * x1 + x2 * x2 + x3 * x3;
#pragma unroll
    for (int off = 32; off; off >>= 1) vs += __shfl_xor(vs, off, 64);
    if (lane == 0) red2[wave] = vs;
    __syncthreads();
    const float var = (red2[0] + red2[1] + red2[2] + red2[3]) * (1.0f / DIMS);
    const float rs = rsqrtf(var + LNEPS);

    const int c = tid * 4;
    float4 gg = *reinterpret_cast<const float4*>(&g[c]);
    float4 bb = *reinterpret_cast<const float4*>(&be[c]);
    float4 o = { x0 * rs * gg.x + bb.x, x1 * rs * gg.y + bb.y,
                 x2 * rs * gg.z + bb.z, x3 * rs * gg.w + bb.w };
    *reinterpret_cast<float4*>(&outp[base]) = o;
    if (DUAL) {
        bf16x4 ob = {(__bf16)o.x, (__bf16)o.y, (__bf16)o.z, (__bf16)o.w};
        *reinterpret_cast<bf16x4*>(&outb[base]) = ob;
    }
}

// ---------------------------------------------------------------------------
extern "C" void kernel_launch(void* const* d_in, const int* in_sizes, int n_in,
                              void* d_out, int out_size, void* d_ws, size_t ws_size,
                              hipStream_t stream)
{
    const float* x   = (const float*)d_in[0];
    const float* Wq  = (const float*)d_in[1];
    const float* bq  = (const float*)d_in[2];
    const float* Wk  = (const float*)d_in[3];
    const float* bk  = (const float*)d_in[4];
    const float* Wv  = (const float*)d_in[5];
    const float* bv  = (const float*)d_in[6];
    const float* Wf  = (const float*)d_in[7];
    const float* bfp = (const float*)d_in[8];
    const float* W1  = (const float*)d_in[9];
    const float* b1  = (const float*)d_in[10];
    const float* W2  = (const float*)d_in[11];
    const float* b2  = (const float*)d_in[12];
    const float* g1  = (const float*)d_in[13];
    const float* be1 = (const float*)d_in[14];
    const float* g2  = (const float*)d_in[15];
    const float* be2 = (const float*)d_in[16];

    float* out   = (float*)d_out;
    float* score = out + (size_t)MROWS * DIMS;   // 134M f32 (also scratch)

    // workspace layout (byte offsets, total exactly 128 MiB):
    char* W = (char*)d_ws;
    bf16_t* xb  = (bf16_t*)(W);                    // [0,16Mi)  -> later aob, W1b/W2b
    bf16_t* aob = xb;
    bf16_t* W1b = (bf16_t*)(W);                    // [0,4Mi)   after proj
    bf16_t* W2b = (bf16_t*)(W + (4u << 20));       // [4,8Mi)
    bf16_t* qb  = (bf16_t*)(W + (16u << 20));      // [16,32Mi) -> later Wfb, yb
    bf16_t* Wfb = qb;
    bf16_t* yb  = qb;
    bf16_t* kb  = (bf16_t*)(W + (32u << 20));      // [32,48Mi) -> h1b lower
    bf16_t* vb  = (bf16_t*)(W + (48u << 20));      // [48,64Mi) -> h1b upper
    bf16_t* h1b = kb;                              // [32,64Mi)
    bf16_t* vtb = (bf16_t*)(W + (64u << 20));      // [64,80Mi) dead before ap
    float*  ap  = (float*)(W + (64u << 20));       // [64,96Mi) -> later f2
    float*  f2  = ap;
    float*  yy  = (float*)(W + (96u << 20));       // [96,128Mi)
    bf16_t* Wqb = (bf16_t*)score;                  // score region as scratch
    bf16_t* Wkb = Wqb + (1u << 20);
    bf16_t* Wvb = Wqb + (2u << 20);

    const dim3 blk(256);

    // casts
    castk<<<4096, blk, 0, stream>>>(x,  xb,  MROWS * DIMS / 8);
    castk<<<512,  blk, 0, stream>>>(Wq, Wqb, DIMS * DIMS / 8);
    castk<<<512,  blk, 0, stream>>>(Wk, Wkb, DIMS * DIMS / 8);
    castk<<<512,  blk, 0, stream>>>(Wv, Wvb, DIMS * DIMS / 8);

    // QKV projections (q pre-scaled by 1/sqrt(HD))
    gemm_bt<true, false, false><<<dim3(8, 64, 1), blk, 0, stream>>>(
        xb, Wqb, bq, qb, MROWS, DIMS, DIMS, DIMS, DIMS, DIMS, 0.125f);
    gemm_bt<true, false, false><<<dim3(8, 64, 1), blk, 0, stream>>>(
        xb, Wkb, bk, kb, MROWS, DIMS, DIMS, DIMS, DIMS, DIMS, 1.0f);
    gemm_bt<true, false, false><<<dim3(8, 64, 1), blk, 0, stream>>>(
        xb, Wvb, bv, vb, MROWS, DIMS, DIMS, DIMS, DIMS, DIMS, 1.0f);

    // V transpose for PV B-operand
    vtrans<<<dim3(16, 128), blk, 0, stream>>>(vb, vtb);

    // QK^T: raw logits into score region (batched over bh)
    gemm_bt<false, false, true><<<dim3(8, 8, 128), blk, 0, stream>>>(
        qb, kb, nullptr, score, SEQ, SEQ, HD, DIMS, DIMS, SEQ, 1.0f);

    castk<<<512, blk, 0, stream>>>(Wf, Wfb, DIMS * DIMS / 8);

    // softmax + probs write + PV
    attn2<<<dim3(64, 128), blk, 0, stream>>>(score, vtb, aob);

    // output projection
    gemm_bt<false, false, false><<<dim3(8, 64, 1), blk, 0, stream>>>(
        aob, Wfb, bfp, ap, MROWS, DIMS, DIMS, DIMS, DIMS, DIMS, 1.0f);

    castk<<<1024, blk, 0, stream>>>(W1, W1b, FFDIM * DIMS / 8);
    castk<<<1024, blk, 0, stream>>>(W2, W2b, FFDIM * DIMS / 8);

    // add + LN1 (f32 + bf16 outputs)
    add_ln<true><<<dim3(MROWS), blk, 0, stream>>>(x, ap, g1, be1, yy, yb);

    // FFN
    gemm_bt<true, true, false><<<dim3(16, 64, 1), blk, 0, stream>>>(
        yb, W1b, b1, h1b, MROWS, FFDIM, DIMS, DIMS, DIMS, FFDIM, 1.0f);
    gemm_bt<false, false, false><<<dim3(8, 64, 1), blk, 0, stream>>>(
        h1b, W2b, b2, f2, MROWS, DIMS, FFDIM, FFDIM, FFDIM, DIMS, 1.0f);

    // add + LN2 -> final out
    add_ln<false><<<dim3(MROWS), blk, 0, stream>>>(yy, f2, g2, be2, out, nullptr);
}